// Round 1
// baseline (436.981 us; speedup 1.0000x reference)
//
#include <hip/hip_runtime.h>
#include <hip/hip_bf16.h>

#define D 64
#define KPER 20

__device__ __forceinline__ float bcast_lane(float v, int l) {
    return __int_as_float(__builtin_amdgcn_readlane(__float_as_int(v), l));
}

template<typename T> __device__ __forceinline__ T to_T(float x);
template<> __device__ __forceinline__ float to_T<float>(float x) { return x; }
template<> __device__ __forceinline__ __hip_bfloat16 to_T<__hip_bfloat16>(float x) { return __float2bfloat16(x); }

template<typename T> __device__ __forceinline__ float to_f(T x);
template<> __device__ __forceinline__ float to_f<float>(float x) { return x; }
template<> __device__ __forceinline__ float to_f<__hip_bfloat16>(__hip_bfloat16 x) { return __bfloat162float(x); }

// out[r,d] = tanh(sum_k h[r,k]*W[k,d] + b[d]); K = 64
template<typename T>
__global__ __launch_bounds__(256) void proj64(const float* __restrict__ h,
        const float* __restrict__ W, const float* __restrict__ b,
        T* __restrict__ out, int nrows) {
    __shared__ float Wl[D * D];
    int tid = threadIdx.x;
    for (int i = tid; i < D * D; i += 256) Wl[i] = W[i];
    __syncthreads();
    int lane = tid & 63;
    int gw = blockIdx.x * 4 + (tid >> 6);
    int nw = gridDim.x * 4;
    float bv = b[lane];
    for (int r = gw; r < nrows; r += nw) {
        float hv = h[(size_t)r * D + lane];
        float acc = bv;
        #pragma unroll
        for (int k = 0; k < 64; ++k)
            acc = fmaf(bcast_lane(hv, k), Wl[k * D + lane], acc);
        out[(size_t)r * D + lane] = to_T<T>(tanhf(acc));
    }
}

// out[r,d] = tanh(sum_k h[r,k]*W[k,d] + b[d]); K = 256
template<typename T>
__global__ __launch_bounds__(256) void proj256(const float* __restrict__ h,
        const float* __restrict__ W, const float* __restrict__ b,
        T* __restrict__ out, int nrows) {
    __shared__ float Wl[256 * D];   // 64 KiB
    int tid = threadIdx.x;
    for (int i = tid; i < 256 * D; i += 256) Wl[i] = W[i];
    __syncthreads();
    int lane = tid & 63;
    int gw = blockIdx.x * 4 + (tid >> 6);
    int nw = gridDim.x * 4;
    float bv = b[lane];
    for (int r = gw; r < nrows; r += nw) {
        float hv[4];
        #pragma unroll
        for (int j = 0; j < 4; ++j) hv[j] = h[(size_t)r * 256 + j * 64 + lane];
        float acc = bv;
        #pragma unroll
        for (int j = 0; j < 4; ++j) {
            #pragma unroll
            for (int k = 0; k < 64; ++k)
                acc = fmaf(bcast_lane(hv[j], k), Wl[(j * 64 + k) * D + lane], acc);
        }
        out[(size_t)r * D + lane] = to_T<T>(tanhf(acc));
    }
}

// One wave per sorted vi-segment (exactly KPER consecutive edges).
// lane = feature dim. Computes per-edge logits, in-wave segment softmax,
// then scatters transition*natt*edges_y into out[eg, vj] via atomics.
template<typename T>
__global__ __launch_bounds__(256) void edge_kernel(
        const float* __restrict__ natt, const int* __restrict__ edges,
        const float* __restrict__ ey, const T* __restrict__ hc,
        const T* __restrict__ hu, const float* __restrict__ relt,
        const float* __restrict__ wsm, const float* __restrict__ fb,
        const float* __restrict__ outw, float* __restrict__ out, int N) {
    int lane = threadIdx.x & 63;
    int s = blockIdx.x * 4 + (threadIdx.x >> 6);
    long base = (long)s * KPER;
    const int* e0 = edges + base * 8;
    int eg = e0[0], vi = e0[1];
    float f1 = to_f<T>(hu[(size_t)vi * D + lane]);
    float na = natt[(size_t)eg * N + vi];
    float w0 = wsm[0 * D + lane], w1 = wsm[1 * D + lane];
    float w2 = wsm[2 * D + lane], w3 = wsm[3 * D + lane];
    float w4 = wsm[4 * D + lane], w5 = wsm[5 * D + lane];
    float w6 = wsm[6 * D + lane], w7 = wsm[7 * D + lane];
    float fbv = fb[lane], owv = outw[lane];
    float myl = -INFINITY;
    int myvj = 0;
    #pragma unroll 4
    for (int e = 0; e < KPER; ++e) {
        const int* er = edges + (base + e) * 8;
        int vj = er[2], rel = er[3], evi = er[6], evj = er[7];
        float F0 = to_f<T>(hc[(size_t)evi * D + lane]);
        float F2 = relt[(size_t)rel * D + lane];
        float F3 = to_f<T>(hc[(size_t)evj * D + lane]);
        float F4 = to_f<T>(hu[(size_t)vj * D + lane]);
        // out_d = fb + f3*(f0*(w0+f2*w1)+f1*(w4+f2*w5)) + f4*(f0*(w2+f2*w3)+f1*(w6+f2*w7))
        float t1 = fmaf(F2, w1, w0);
        float t2 = fmaf(F2, w5, w4);
        float t3 = fmaf(F2, w3, w2);
        float t4 = fmaf(F2, w7, w6);
        float u = fmaf(F0, t1, f1 * t2);
        float v = fmaf(F0, t3, f1 * t4);
        float o = fmaf(F3, u, fmaf(F4, v, fbv));
        o = fmaxf(o, 0.0f) * owv;    // relu(out)*out_w ; out_b cancels in softmax
        #pragma unroll
        for (int m = 1; m < 64; m <<= 1) o += __shfl_xor(o, m);
        if (lane == e) { myl = o; myvj = vj; }
    }
    // in-wave softmax over lanes 0..KPER-1 (others hold -inf -> ex = 0)
    float mx = myl;
    #pragma unroll
    for (int m = 1; m < 64; m <<= 1) mx = fmaxf(mx, __shfl_xor(mx, m));
    float ex = __expf(myl - mx);
    float den = ex;
    #pragma unroll
    for (int m = 1; m < 64; m <<= 1) den += __shfl_xor(den, m);
    if (lane < KPER) {
        float t = (ex / den) * na * ey[base + lane];
        atomicAdd(out + (size_t)eg * N + myvj, t);
    }
}

extern "C" void kernel_launch(void* const* d_in, const int* in_sizes, int n_in,
                              void* d_out, int out_size, void* d_ws, size_t ws_size,
                              hipStream_t stream) {
    const float* natt = (const float*)d_in[0];
    const int*   edges = (const int*)d_in[1];
    const float* ey   = (const float*)d_in[2];
    const float* hun  = (const float*)d_in[3];
    const float* hcon = (const float*)d_in[4];
    const float* Wc   = (const float*)d_in[5];
    const float* bc   = (const float*)d_in[6];
    const float* Wu   = (const float*)d_in[7];
    const float* bu   = (const float*)d_in[8];
    const float* relt = (const float*)d_in[9];
    const float* wsm  = (const float*)d_in[10];
    const float* fb   = (const float*)d_in[11];
    const float* outw = (const float*)d_in[12];
    float* out = (float*)d_out;

    int E    = in_sizes[2];          // 400000 edges
    int S    = E / KPER;             // 20000 sorted vi segments
    int nmem = in_sizes[4] / D;      // 131072 hidden_con rows
    int N    = in_sizes[3] / 256;    // 50000 nodes

    hipMemsetAsync(d_out, 0, (size_t)out_size * sizeof(float), stream);

    size_t need_f32 = ((size_t)nmem + (size_t)N) * D * sizeof(float);
    if (ws_size >= need_f32) {
        float* hc = (float*)d_ws;
        float* hu = hc + (size_t)nmem * D;
        proj64<float><<<1024, 256, 0, stream>>>(hcon, Wc, bc, hc, nmem);
        proj256<float><<<512, 256, 0, stream>>>(hun, Wu, bu, hu, N);
        edge_kernel<float><<<S / 4, 256, 0, stream>>>(natt, edges, ey, hc, hu,
                                                      relt, wsm, fb, outw, out, N);
    } else {
        __hip_bfloat16* hc = (__hip_bfloat16*)d_ws;
        __hip_bfloat16* hu = hc + (size_t)nmem * D;
        proj64<__hip_bfloat16><<<1024, 256, 0, stream>>>(hcon, Wc, bc, hc, nmem);
        proj256<__hip_bfloat16><<<512, 256, 0, stream>>>(hun, Wu, bu, hu, N);
        edge_kernel<__hip_bfloat16><<<S / 4, 256, 0, stream>>>(natt, edges, ey, hc, hu,
                                                               relt, wsm, fb, outw, out, N);
    }
}

// Round 2
// 233.022 us; speedup vs baseline: 1.8753x; 1.8753x over previous
//
#include <hip/hip_runtime.h>
#include <hip/hip_bf16.h>

#define D 64
#define KPER 20

typedef __attribute__((ext_vector_type(8))) short short8;
typedef __attribute__((ext_vector_type(4))) float floatx4;

__device__ __forceinline__ short f2bf(float x) {
    __hip_bfloat16 h = __float2bfloat16(x);
    return *reinterpret_cast<short*>(&h);
}

template<typename T> __device__ __forceinline__ T to_T(float x);
template<> __device__ __forceinline__ float to_T<float>(float x) { return x; }
template<> __device__ __forceinline__ __hip_bfloat16 to_T<__hip_bfloat16>(float x) { return __float2bfloat16(x); }

template<typename T> __device__ __forceinline__ float to_f(T x);
template<> __device__ __forceinline__ float to_f<float>(float x) { return x; }
template<> __device__ __forceinline__ float to_f<__hip_bfloat16>(__hip_bfloat16 x) { return __bfloat162float(x); }

// out[r,d] = tanh(h[r,:] @ W[:,d] + b[d]) via bf16 MFMA, fp32 accumulate.
// One wave per 16-row tile; 4 col-tiles of 16 cover D=64.
// A frag: A[m=lane&15][k=quad*8+j]; B frag: B[n=lane&15][k=quad*8+j];
// C/D: col=lane&15, row=quad*4+reg.
template<int K, typename T>
__global__ __launch_bounds__(256) void proj_mfma(const float* __restrict__ h,
        const float* __restrict__ W, const float* __restrict__ b,
        T* __restrict__ out, int ntiles) {
    constexpr int PAD = 8;                 // keep 16B alignment, break bank stride
    __shared__ short Wl[64 * (K + PAD)];   // W transposed, bf16: Wl[n][k]
    int tid = threadIdx.x;
    for (int i = tid; i < K * 64; i += 256) {
        int k = i >> 6, n = i & 63;
        Wl[n * (K + PAD) + k] = f2bf(W[i]);
    }
    __syncthreads();
    int lane = tid & 63;
    int m = lane & 15, quad = lane >> 4;
    int w = tid >> 6;
    for (int rt = blockIdx.x * 4 + w; rt < ntiles; rt += gridDim.x * 4) {
        floatx4 acc[4];
        #pragma unroll
        for (int ct = 0; ct < 4; ++ct) acc[ct] = floatx4{0.f, 0.f, 0.f, 0.f};
        const float* hrow = h + (size_t)(rt * 16 + m) * K + quad * 8;
        #pragma unroll
        for (int kt = 0; kt < K / 32; ++kt) {
            floatx4 a0 = *(const floatx4*)(hrow + kt * 32);
            floatx4 a1 = *(const floatx4*)(hrow + kt * 32 + 4);
            short8 af;
            af[0] = f2bf(a0[0]); af[1] = f2bf(a0[1]);
            af[2] = f2bf(a0[2]); af[3] = f2bf(a0[3]);
            af[4] = f2bf(a1[0]); af[5] = f2bf(a1[1]);
            af[6] = f2bf(a1[2]); af[7] = f2bf(a1[3]);
            #pragma unroll
            for (int ct = 0; ct < 4; ++ct) {
                short8 bf = *(const short8*)(&Wl[(ct * 16 + m) * (K + PAD) + kt * 32 + quad * 8]);
                acc[ct] = __builtin_amdgcn_mfma_f32_16x16x32_bf16(af, bf, acc[ct], 0, 0, 0);
            }
        }
        #pragma unroll
        for (int ct = 0; ct < 4; ++ct) {
            int col = ct * 16 + m;
            float bv = b[col];
            #pragma unroll
            for (int reg = 0; reg < 4; ++reg) {
                int row = rt * 16 + quad * 4 + reg;
                out[(size_t)row * 64 + col] = to_T<T>(tanhf(acc[ct][reg] + bv));
            }
        }
    }
}

// One wave per sorted vi-segment (exactly KPER consecutive edges).
template<typename T>
__global__ __launch_bounds__(256) void edge_kernel(
        const float* __restrict__ natt, const int* __restrict__ edges,
        const float* __restrict__ ey, const T* __restrict__ hc,
        const T* __restrict__ hu, const float* __restrict__ relt,
        const float* __restrict__ wsm, const float* __restrict__ fb,
        const float* __restrict__ outw, float* __restrict__ out, int N) {
    int lane = threadIdx.x & 63;
    int s = blockIdx.x * 4 + (threadIdx.x >> 6);
    long base = (long)s * KPER;
    const int* e0 = edges + base * 8;
    int eg = e0[0], vi = e0[1];
    float f1 = to_f<T>(hu[(size_t)vi * D + lane]);
    float na = natt[(size_t)eg * N + vi];
    float w0 = wsm[0 * D + lane], w1 = wsm[1 * D + lane];
    float w2 = wsm[2 * D + lane], w3 = wsm[3 * D + lane];
    float w4 = wsm[4 * D + lane], w5 = wsm[5 * D + lane];
    float w6 = wsm[6 * D + lane], w7 = wsm[7 * D + lane];
    float fbv = fb[lane], owv = outw[lane];
    float myl = -INFINITY;
    int myvj = 0;
    #pragma unroll 4
    for (int e = 0; e < KPER; ++e) {
        const int* er = edges + (base + e) * 8;
        int vj = er[2], rel = er[3], evi = er[6], evj = er[7];
        float F0 = to_f<T>(hc[(size_t)evi * D + lane]);
        float F2 = relt[(size_t)rel * D + lane];
        float F3 = to_f<T>(hc[(size_t)evj * D + lane]);
        float F4 = to_f<T>(hu[(size_t)vj * D + lane]);
        float t1 = fmaf(F2, w1, w0);
        float t2 = fmaf(F2, w5, w4);
        float t3 = fmaf(F2, w3, w2);
        float t4 = fmaf(F2, w7, w6);
        float u = fmaf(F0, t1, f1 * t2);
        float v = fmaf(F0, t3, f1 * t4);
        float o = fmaf(F3, u, fmaf(F4, v, fbv));
        o = fmaxf(o, 0.0f) * owv;    // relu(out)*out_w ; out_b cancels in softmax
        #pragma unroll
        for (int mm = 1; mm < 64; mm <<= 1) o += __shfl_xor(o, mm);
        if (lane == e) { myl = o; myvj = vj; }
    }
    float mx = myl;
    #pragma unroll
    for (int mm = 1; mm < 64; mm <<= 1) mx = fmaxf(mx, __shfl_xor(mx, mm));
    float ex = __expf(myl - mx);
    float den = ex;
    #pragma unroll
    for (int mm = 1; mm < 64; mm <<= 1) den += __shfl_xor(den, mm);
    if (lane < KPER) {
        float t = (ex / den) * na * ey[base + lane];
        atomicAdd(out + (size_t)eg * N + myvj, t);
    }
}

extern "C" void kernel_launch(void* const* d_in, const int* in_sizes, int n_in,
                              void* d_out, int out_size, void* d_ws, size_t ws_size,
                              hipStream_t stream) {
    const float* natt = (const float*)d_in[0];
    const int*   edges = (const int*)d_in[1];
    const float* ey   = (const float*)d_in[2];
    const float* hun  = (const float*)d_in[3];
    const float* hcon = (const float*)d_in[4];
    const float* Wc   = (const float*)d_in[5];
    const float* bc   = (const float*)d_in[6];
    const float* Wu   = (const float*)d_in[7];
    const float* bu   = (const float*)d_in[8];
    const float* relt = (const float*)d_in[9];
    const float* wsm  = (const float*)d_in[10];
    const float* fb   = (const float*)d_in[11];
    const float* outw = (const float*)d_in[12];
    float* out = (float*)d_out;

    int E    = in_sizes[2];          // 400000 edges
    int S    = E / KPER;             // 20000 sorted vi segments
    int nmem = in_sizes[4] / D;      // 131072 hidden_con rows
    int N    = in_sizes[3] / 256;    // 50000 nodes

    hipMemsetAsync(d_out, 0, (size_t)out_size * sizeof(float), stream);

    int t64  = nmem / 16;            // 8192 row-tiles
    int t256 = N / 16;               // 3125 row-tiles

    size_t need_f32 = ((size_t)nmem + (size_t)N) * D * sizeof(float);
    if (ws_size >= need_f32) {
        float* hc = (float*)d_ws;
        float* hu = hc + (size_t)nmem * D;
        proj_mfma<64, float><<<(t64 + 3) / 4, 256, 0, stream>>>(hcon, Wc, bc, hc, t64);
        proj_mfma<256, float><<<(t256 + 3) / 4, 256, 0, stream>>>(hun, Wu, bu, hu, t256);
        edge_kernel<float><<<S / 4, 256, 0, stream>>>(natt, edges, ey, hc, hu,
                                                      relt, wsm, fb, outw, out, N);
    } else {
        __hip_bfloat16* hc = (__hip_bfloat16*)d_ws;
        __hip_bfloat16* hu = hc + (size_t)nmem * D;
        proj_mfma<64, __hip_bfloat16><<<(t64 + 3) / 4, 256, 0, stream>>>(hcon, Wc, bc, hc, t64);
        proj_mfma<256, __hip_bfloat16><<<(t256 + 3) / 4, 256, 0, stream>>>(hun, Wu, bu, hu, t256);
        edge_kernel<__hip_bfloat16><<<S / 4, 256, 0, stream>>>(natt, edges, ey, hc, hu,
                                                               relt, wsm, fb, outw, out, N);
    }
}

// Round 3
// 224.698 us; speedup vs baseline: 1.9447x; 1.0370x over previous
//
#include <hip/hip_runtime.h>
#include <hip/hip_bf16.h>

#define D 64
#define KPER 20

typedef __attribute__((ext_vector_type(8))) short short8;
typedef __attribute__((ext_vector_type(4))) float floatx4;

__device__ __forceinline__ short f2bf(float x) {
    __hip_bfloat16 h = __float2bfloat16(x);
    return *reinterpret_cast<short*>(&h);
}

template<typename T> __device__ __forceinline__ T to_T(float x);
template<> __device__ __forceinline__ float to_T<float>(float x) { return x; }
template<> __device__ __forceinline__ __hip_bfloat16 to_T<__hip_bfloat16>(float x) { return __float2bfloat16(x); }

template<typename T> __device__ __forceinline__ float to_f(T x);
template<> __device__ __forceinline__ float to_f<float>(float x) { return x; }
template<> __device__ __forceinline__ float to_f<__hip_bfloat16>(__hip_bfloat16 x) { return __bfloat162float(x); }

__device__ __forceinline__ float fast_tanh(float x) {
    float xc = fminf(fmaxf(x, -15.f), 15.f);
    float e = __expf(2.f * xc);
    return 1.f - 2.f * __builtin_amdgcn_rcpf(1.f + e);
}

// ---- DPP 64-lane reductions (VALU pipe, no DS) -------------------------
template<int CTRL>
__device__ __forceinline__ float dpp_add(float x) {
    int t = __builtin_amdgcn_update_dpp(0, __float_as_int(x), CTRL, 0xf, 0xf, true);
    return x + __int_as_float(t);
}
template<int CTRL>
__device__ __forceinline__ float dpp_max(float x) {
    int xi = __float_as_int(x);
    int t = __builtin_amdgcn_update_dpp(xi, xi, CTRL, 0xf, 0xf, false);
    return fmaxf(x, __int_as_float(t));
}
// row_shr:1=0x111, :2=0x112, :4=0x114, :8=0x118, row_bcast15=0x142, row_bcast31=0x143
__device__ __forceinline__ float wave_sum_b(float x) {
    x = dpp_add<0x111>(x); x = dpp_add<0x112>(x);
    x = dpp_add<0x114>(x); x = dpp_add<0x118>(x);
    x = dpp_add<0x142>(x); x = dpp_add<0x143>(x);
    return __int_as_float(__builtin_amdgcn_readlane(__float_as_int(x), 63));
}
__device__ __forceinline__ float wave_max_b(float x) {
    x = dpp_max<0x111>(x); x = dpp_max<0x112>(x);
    x = dpp_max<0x114>(x); x = dpp_max<0x118>(x);
    x = dpp_max<0x142>(x); x = dpp_max<0x143>(x);
    return __int_as_float(__builtin_amdgcn_readlane(__float_as_int(x), 63));
}

// ---- projection body: out[r,d]=tanh(h[r,:]@W[:,d]+b[d]), bf16 MFMA -----
// B-fragments held in registers (no LDS, no barrier). CTN col-tiles of 16
// starting at ct0*16. One wave per 16-row tile iteration.
template<int K, int CTN, typename T>
__device__ __forceinline__ void proj_body(const float* __restrict__ h,
        const float* __restrict__ W, const float* __restrict__ b,
        T* __restrict__ out, int ct0, int rt0, int rtstride, int ntiles) {
    constexpr int KT = K / 32;
    int lane = threadIdx.x & 63;
    int m = lane & 15, quad = lane >> 4;
    short8 bfr[CTN][KT];
    #pragma unroll
    for (int ct = 0; ct < CTN; ++ct)
        #pragma unroll
        for (int kt = 0; kt < KT; ++kt)
            #pragma unroll
            for (int j = 0; j < 8; ++j)
                bfr[ct][kt][j] = f2bf(W[(size_t)(kt * 32 + quad * 8 + j) * 64 + (ct0 + ct) * 16 + m]);
    float bv[CTN];
    #pragma unroll
    for (int ct = 0; ct < CTN; ++ct) bv[ct] = b[(ct0 + ct) * 16 + m];
    for (int rt = rt0; rt < ntiles; rt += rtstride) {
        floatx4 acc[CTN];
        #pragma unroll
        for (int ct = 0; ct < CTN; ++ct) acc[ct] = floatx4{0.f, 0.f, 0.f, 0.f};
        const float* hrow = h + (size_t)(rt * 16 + m) * K + quad * 8;
        #pragma unroll
        for (int kt = 0; kt < KT; ++kt) {
            floatx4 a0 = *(const floatx4*)(hrow + kt * 32);
            floatx4 a1 = *(const floatx4*)(hrow + kt * 32 + 4);
            short8 af;
            af[0] = f2bf(a0[0]); af[1] = f2bf(a0[1]);
            af[2] = f2bf(a0[2]); af[3] = f2bf(a0[3]);
            af[4] = f2bf(a1[0]); af[5] = f2bf(a1[1]);
            af[6] = f2bf(a1[2]); af[7] = f2bf(a1[3]);
            #pragma unroll
            for (int ct = 0; ct < CTN; ++ct)
                acc[ct] = __builtin_amdgcn_mfma_f32_16x16x32_bf16(af, bfr[ct][kt], acc[ct], 0, 0, 0);
        }
        #pragma unroll
        for (int ct = 0; ct < CTN; ++ct) {
            int col = (ct0 + ct) * 16 + m;
            #pragma unroll
            for (int reg = 0; reg < 4; ++reg) {
                int row = rt * 16 + quad * 4 + reg;
                out[(size_t)row * 64 + col] = to_T<T>(fast_tanh(acc[ct][reg] + bv[ct]));
            }
        }
    }
}

// Fused: blocks [0,g64) do the K=64 projection, the rest do K=256 (split
// into 2 column-halves so B-frags stay in 64 VGPRs).
template<typename T>
__global__ __launch_bounds__(256) void proj_fused(
        const float* __restrict__ hcon, const float* __restrict__ Wc, const float* __restrict__ bc,
        const float* __restrict__ hun, const float* __restrict__ Wu, const float* __restrict__ bu,
        T* __restrict__ hc, T* __restrict__ hu, int t64, int t256, int g64) {
    int w = threadIdx.x >> 6;
    if ((int)blockIdx.x < g64) {
        int wid = blockIdx.x * 4 + w;
        proj_body<64, 4, T>(hcon, Wc, bc, hc, 0, wid, g64 * 4, t64);
    } else {
        int g256 = gridDim.x - g64;
        int wid = (blockIdx.x - g64) * 4 + w;
        int half = wid & 1;                      // fixed per wave -> B-frags loaded once
        proj_body<256, 2, T>(hun, Wu, bu, hu, half * 2, wid >> 1, (g256 * 4) >> 1, t256);
    }
}

// One wave per sorted vi-segment (exactly KPER consecutive edges).
template<typename T>
__global__ __launch_bounds__(256) void edge_kernel(
        const float* __restrict__ natt, const int* __restrict__ edges,
        const float* __restrict__ ey, const T* __restrict__ hc,
        const T* __restrict__ hu, const float* __restrict__ relt,
        const float* __restrict__ wsm, const float* __restrict__ fb,
        const float* __restrict__ outw, float* __restrict__ out, int N) {
    int lane = threadIdx.x & 63;
    int s = blockIdx.x * 4 + (threadIdx.x >> 6);
    long base = (long)s * KPER;
    const int* e0 = edges + base * 8;
    int eg = e0[0], vi = e0[1];
    float f1 = to_f<T>(hu[(size_t)vi * D + lane]);
    float na = natt[(size_t)eg * N + vi];
    float w0 = wsm[0 * D + lane], w1 = wsm[1 * D + lane];
    float w2 = wsm[2 * D + lane], w3 = wsm[3 * D + lane];
    float w4 = wsm[4 * D + lane], w5 = wsm[5 * D + lane];
    float w6 = wsm[6 * D + lane], w7 = wsm[7 * D + lane];
    float fbv = fb[lane], owv = outw[lane];
    float myl = -INFINITY;
    int myvj = 0;
    #pragma unroll 4
    for (int e = 0; e < KPER; ++e) {
        const int* er = edges + (base + e) * 8;
        int vj = er[2], rel = er[3], evi = er[6], evj = er[7];
        float F0 = to_f<T>(hc[(size_t)evi * D + lane]);
        float F2 = relt[(size_t)rel * D + lane];
        float F3 = to_f<T>(hc[(size_t)evj * D + lane]);
        float F4 = to_f<T>(hu[(size_t)vj * D + lane]);
        float t1 = fmaf(F2, w1, w0);
        float t2 = fmaf(F2, w5, w4);
        float t3 = fmaf(F2, w3, w2);
        float t4 = fmaf(F2, w7, w6);
        float u = fmaf(F0, t1, f1 * t2);
        float v = fmaf(F0, t3, f1 * t4);
        float o = fmaf(F3, u, fmaf(F4, v, fbv));
        o = fmaxf(o, 0.0f) * owv;    // relu(out)*out_w ; out_b cancels in softmax
        float tot = wave_sum_b(o);   // DPP reduce, VALU pipe
        bool mine = (lane == e);
        myl = mine ? tot : myl;
        myvj = mine ? vj : myvj;
    }
    float mx = wave_max_b(myl);
    float ex = __expf(myl - mx);     // lanes >= KPER hold -inf -> ex = 0
    float den = wave_sum_b(ex);
    if (lane < KPER) {
        float t = (ex / den) * na * ey[base + lane];
        atomicAdd(out + (size_t)eg * N + myvj, t);
    }
}

extern "C" void kernel_launch(void* const* d_in, const int* in_sizes, int n_in,
                              void* d_out, int out_size, void* d_ws, size_t ws_size,
                              hipStream_t stream) {
    const float* natt = (const float*)d_in[0];
    const int*   edges = (const int*)d_in[1];
    const float* ey   = (const float*)d_in[2];
    const float* hun  = (const float*)d_in[3];
    const float* hcon = (const float*)d_in[4];
    const float* Wc   = (const float*)d_in[5];
    const float* bc   = (const float*)d_in[6];
    const float* Wu   = (const float*)d_in[7];
    const float* bu   = (const float*)d_in[8];
    const float* relt = (const float*)d_in[9];
    const float* wsm  = (const float*)d_in[10];
    const float* fb   = (const float*)d_in[11];
    const float* outw = (const float*)d_in[12];
    float* out = (float*)d_out;

    int E    = in_sizes[2];          // 400000 edges
    int S    = E / KPER;             // 20000 sorted vi segments
    int nmem = in_sizes[4] / D;      // 131072 hidden_con rows
    int N    = in_sizes[3] / 256;    // 50000 nodes

    hipMemsetAsync(d_out, 0, (size_t)out_size * sizeof(float), stream);

    int t64  = nmem / 16;            // 8192 row-tiles
    int t256 = N / 16;               // 3125 row-tiles (N divisible by 16? 50000/16=3125)
    int g64  = 512, g256 = 512;

    size_t need_f32 = ((size_t)nmem + (size_t)N) * D * sizeof(float);
    if (ws_size >= need_f32) {
        float* hc = (float*)d_ws;
        float* hu = hc + (size_t)nmem * D;
        proj_fused<float><<<g64 + g256, 256, 0, stream>>>(hcon, Wc, bc, hun, Wu, bu,
                                                          hc, hu, t64, t256, g64);
        edge_kernel<float><<<S / 4, 256, 0, stream>>>(natt, edges, ey, hc, hu,
                                                      relt, wsm, fb, outw, out, N);
    } else {
        __hip_bfloat16* hc = (__hip_bfloat16*)d_ws;
        __hip_bfloat16* hu = hc + (size_t)nmem * D;
        proj_fused<__hip_bfloat16><<<g64 + g256, 256, 0, stream>>>(hcon, Wc, bc, hun, Wu, bu,
                                                                   hc, hu, t64, t256, g64);
        edge_kernel<__hip_bfloat16><<<S / 4, 256, 0, stream>>>(natt, edges, ey, hc, hu,
                                                               relt, wsm, fb, outw, out, N);
    }
}

// Round 4
// 207.174 us; speedup vs baseline: 2.1092x; 1.0846x over previous
//
#include <hip/hip_runtime.h>
#include <hip/hip_bf16.h>
#include <type_traits>

#define D 64
#define KPER 20

typedef __attribute__((ext_vector_type(8))) short short8;
typedef __attribute__((ext_vector_type(4))) float floatx4;

__device__ __forceinline__ unsigned short f2bfu(float x) {
    __hip_bfloat16 h = __float2bfloat16(x);
    return *reinterpret_cast<unsigned short*>(&h);
}
__device__ __forceinline__ float bfu2f(unsigned short u) {
    return __uint_as_float(((unsigned)u) << 16);
}

__device__ __forceinline__ float fast_tanh(float x) {
    float xc = fminf(fmaxf(x, -15.f), 15.f);
    float e = __expf(2.f * xc);
    return 1.f - 2.f * __builtin_amdgcn_rcpf(1.f + e);
}

// ---- DPP 64-lane reductions (VALU pipe, no DS) -------------------------
template<int CTRL>
__device__ __forceinline__ float dpp_add(float x) {
    int t = __builtin_amdgcn_update_dpp(0, __float_as_int(x), CTRL, 0xf, 0xf, true);
    return x + __int_as_float(t);
}
template<int CTRL>
__device__ __forceinline__ float dpp_max(float x) {
    int xi = __float_as_int(x);
    int t = __builtin_amdgcn_update_dpp(xi, xi, CTRL, 0xf, 0xf, false);
    return fmaxf(x, __int_as_float(t));
}
__device__ __forceinline__ float wave_sum_b(float x) {
    x = dpp_add<0x111>(x); x = dpp_add<0x112>(x);
    x = dpp_add<0x114>(x); x = dpp_add<0x118>(x);
    x = dpp_add<0x142>(x); x = dpp_add<0x143>(x);
    return __int_as_float(__builtin_amdgcn_readlane(__float_as_int(x), 63));
}
__device__ __forceinline__ float wave_max_b(float x) {
    x = dpp_max<0x111>(x); x = dpp_max<0x112>(x);
    x = dpp_max<0x114>(x); x = dpp_max<0x118>(x);
    x = dpp_max<0x142>(x); x = dpp_max<0x143>(x);
    return __int_as_float(__builtin_amdgcn_readlane(__float_as_int(x), 63));
}

// ---- compile-time unroll helper ---------------------------------------
template<int I, int N, typename F>
__device__ __forceinline__ void static_for(F&& f) {
    if constexpr (I < N) {
        f(std::integral_constant<int, I>{});
        static_for<I + 1, N>(f);
    }
}

// pick metadata slot (compile-time) from the 3 cooperative regs -> SGPR
template<int SLOT>
__device__ __forceinline__ int get_slot(int m0, int m1, int m2) {
    if constexpr (SLOT < 64)       return __builtin_amdgcn_readlane(m0, SLOT);
    else if constexpr (SLOT < 128) return __builtin_amdgcn_readlane(m1, SLOT - 64);
    else                           return __builtin_amdgcn_readlane(m2, SLOT - 128);
}

// ---- projection body: out[r,d]=tanh(h[r,:]@W[:,d]+b[d]), bf16 MFMA -----
template<int K, int CTN>
__device__ __forceinline__ void proj_body(const float* __restrict__ h,
        const float* __restrict__ W, const float* __restrict__ b,
        unsigned short* __restrict__ out, int ct0, int rt0, int rtstride, int ntiles) {
    constexpr int KT = K / 32;
    int lane = threadIdx.x & 63;
    int m = lane & 15, quad = lane >> 4;
    short8 bfr[CTN][KT];
    #pragma unroll
    for (int ct = 0; ct < CTN; ++ct)
        #pragma unroll
        for (int kt = 0; kt < KT; ++kt)
            #pragma unroll
            for (int j = 0; j < 8; ++j)
                bfr[ct][kt][j] = (short)f2bfu(W[(size_t)(kt * 32 + quad * 8 + j) * 64 + (ct0 + ct) * 16 + m]);
    float bv[CTN];
    #pragma unroll
    for (int ct = 0; ct < CTN; ++ct) bv[ct] = b[(ct0 + ct) * 16 + m];
    for (int rt = rt0; rt < ntiles; rt += rtstride) {
        floatx4 acc[CTN];
        #pragma unroll
        for (int ct = 0; ct < CTN; ++ct) acc[ct] = floatx4{0.f, 0.f, 0.f, 0.f};
        const float* hrow = h + (size_t)(rt * 16 + m) * K + quad * 8;
        #pragma unroll
        for (int kt = 0; kt < KT; ++kt) {
            floatx4 a0 = *(const floatx4*)(hrow + kt * 32);
            floatx4 a1 = *(const floatx4*)(hrow + kt * 32 + 4);
            short8 af;
            af[0] = (short)f2bfu(a0[0]); af[1] = (short)f2bfu(a0[1]);
            af[2] = (short)f2bfu(a0[2]); af[3] = (short)f2bfu(a0[3]);
            af[4] = (short)f2bfu(a1[0]); af[5] = (short)f2bfu(a1[1]);
            af[6] = (short)f2bfu(a1[2]); af[7] = (short)f2bfu(a1[3]);
            #pragma unroll
            for (int ct = 0; ct < CTN; ++ct)
                acc[ct] = __builtin_amdgcn_mfma_f32_16x16x32_bf16(af, bfr[ct][kt], acc[ct], 0, 0, 0);
        }
        #pragma unroll
        for (int ct = 0; ct < CTN; ++ct) {
            int col = (ct0 + ct) * 16 + m;
            #pragma unroll
            for (int reg = 0; reg < 4; ++reg) {
                int row = rt * 16 + quad * 4 + reg;
                out[(size_t)row * 64 + col] = f2bfu(fast_tanh(acc[ct][reg] + bv[ct]));
            }
        }
    }
}

// Fused: [0,g64) K=64 proj; [g64,g64+g256) K=256 proj; last RELB blocks
// convert rel_table fp32 -> bf16.
#define RELB 16
__global__ __launch_bounds__(256) void proj_fused(
        const float* __restrict__ hcon, const float* __restrict__ Wc, const float* __restrict__ bc,
        const float* __restrict__ hun, const float* __restrict__ Wu, const float* __restrict__ bu,
        const float* __restrict__ relf, unsigned short* __restrict__ hc,
        unsigned short* __restrict__ hu, unsigned short* __restrict__ relb,
        int t64, int t256, int g64, int g256, int nrel) {
    int bid = blockIdx.x;
    int w = threadIdx.x >> 6;
    if (bid < g64) {
        int wid = bid * 4 + w;
        proj_body<64, 4>(hcon, Wc, bc, hc, 0, wid, g64 * 4, t64);
    } else if (bid < g64 + g256) {
        int wid = (bid - g64) * 4 + w;
        int half = wid & 1;                      // fixed per wave -> B-frags loaded once
        proj_body<256, 2>(hun, Wu, bu, hu, half * 2, wid >> 1, (g256 * 4) >> 1, t256);
    } else {
        int tid = (bid - g64 - g256) * 256 + threadIdx.x;
        for (int i = tid; i < nrel; i += RELB * 256) relb[i] = f2bfu(relf[i]);
    }
}

// One wave per sorted vi-segment (KPER consecutive edges). Metadata loaded
// cooperatively -> v_readlane -> SGPR gather bases; bf16 feature tables.
__global__ __launch_bounds__(256) void edge_kernel(
        const float* __restrict__ natt, const int* __restrict__ edges,
        const float* __restrict__ ey, const unsigned short* __restrict__ hc,
        const unsigned short* __restrict__ hu, const unsigned short* __restrict__ relt,
        const float* __restrict__ wsm, const float* __restrict__ fb,
        const float* __restrict__ outw, float* __restrict__ out, int N) {
    int lane = threadIdx.x & 63;
    int s = blockIdx.x * 4 + (threadIdx.x >> 6);
    long base = (long)s * KPER;
    const int* eb = edges + base * 8;          // 160 ints of segment metadata
    int m0 = eb[lane];
    int m1 = eb[64 + lane];
    int m2 = (lane < 32) ? eb[128 + lane] : 0; // guard: last segment ends at 160
    int eg = get_slot<0>(m0, m1, m2);
    int vi = get_slot<1>(m0, m1, m2);
    float f1 = bfu2f(hu[(size_t)vi * D + lane]);
    float na = natt[(size_t)eg * N + vi];      // uniform -> s_load
    float w0 = wsm[0 * D + lane], w1 = wsm[1 * D + lane];
    float w2 = wsm[2 * D + lane], w3 = wsm[3 * D + lane];
    float w4 = wsm[4 * D + lane], w5 = wsm[5 * D + lane];
    float w6 = wsm[6 * D + lane], w7 = wsm[7 * D + lane];
    float fbv = fb[lane], owv = outw[lane];
    float myl = -INFINITY;
    int myvj = 0;
    static_for<0, KPER>([&](auto ec) {
        constexpr int e = decltype(ec)::value;
        int vj  = get_slot<e * 8 + 2>(m0, m1, m2);
        int rel = get_slot<e * 8 + 3>(m0, m1, m2);
        int evi = get_slot<e * 8 + 6>(m0, m1, m2);
        int evj = get_slot<e * 8 + 7>(m0, m1, m2);
        float F0 = bfu2f(hc[(size_t)evi * D + lane]);
        float F2 = bfu2f(relt[(size_t)rel * D + lane]);
        float F3 = bfu2f(hc[(size_t)evj * D + lane]);
        float F4 = bfu2f(hu[(size_t)vj * D + lane]);
        float t1 = fmaf(F2, w1, w0);
        float t2 = fmaf(F2, w5, w4);
        float t3 = fmaf(F2, w3, w2);
        float t4 = fmaf(F2, w7, w6);
        float u = fmaf(F0, t1, f1 * t2);
        float v = fmaf(F0, t3, f1 * t4);
        float o = fmaf(F3, u, fmaf(F4, v, fbv));
        o = fmaxf(o, 0.0f) * owv;    // relu(out)*out_w ; out_b cancels in softmax
        float tot = wave_sum_b(o);   // DPP reduce, VALU pipe
        bool mine = (lane == e);
        myl = mine ? tot : myl;
        myvj = mine ? vj : myvj;
    });
    float mx = wave_max_b(myl);
    float ex = __expf(myl - mx);     // lanes >= KPER hold -inf -> ex = 0
    float den = wave_sum_b(ex);
    if (lane < KPER) {
        float t = (ex / den) * na * ey[base + lane];
        atomicAdd(out + (size_t)eg * N + myvj, t);
    }
}

extern "C" void kernel_launch(void* const* d_in, const int* in_sizes, int n_in,
                              void* d_out, int out_size, void* d_ws, size_t ws_size,
                              hipStream_t stream) {
    const float* natt = (const float*)d_in[0];
    const int*   edges = (const int*)d_in[1];
    const float* ey   = (const float*)d_in[2];
    const float* hun  = (const float*)d_in[3];
    const float* hcon = (const float*)d_in[4];
    const float* Wc   = (const float*)d_in[5];
    const float* bc   = (const float*)d_in[6];
    const float* Wu   = (const float*)d_in[7];
    const float* bu   = (const float*)d_in[8];
    const float* relt = (const float*)d_in[9];
    const float* wsm  = (const float*)d_in[10];
    const float* fb   = (const float*)d_in[11];
    const float* outw = (const float*)d_in[12];
    float* out = (float*)d_out;

    int E    = in_sizes[2];          // 400000 edges
    int S    = E / KPER;             // 20000 sorted vi segments
    int nmem = in_sizes[4] / D;      // 131072 hidden_con rows
    int N    = in_sizes[3] / 256;    // 50000 nodes
    int nrel = in_sizes[9];          // 500*64

    hipMemsetAsync(d_out, 0, (size_t)out_size * sizeof(float), stream);

    int t64  = nmem / 16;            // 8192 row-tiles
    int t256 = N / 16;               // 3125 row-tiles
    int g64  = 512, g256 = 512;

    unsigned short* hc = (unsigned short*)d_ws;
    unsigned short* hu = hc + (size_t)nmem * D;
    unsigned short* rb = hu + (size_t)N * D;

    proj_fused<<<g64 + g256 + RELB, 256, 0, stream>>>(hcon, Wc, bc, hun, Wu, bu,
                                                      relt, hc, hu, rb,
                                                      t64, t256, g64, g256, nrel);
    edge_kernel<<<S / 4, 256, 0, stream>>>(natt, edges, ey, hc, hu, rb,
                                           wsm, fb, outw, out, N);
}